// Round 14
// baseline (235.243 us; speedup 1.0000x reference)
//
#include <hip/hip_runtime.h>
#include <hip/hip_bf16.h>

#define E_    8
#define H_    512
#define DFF_  2048
#define T_    8192
#define NSLOT (2 * T_)

typedef float  f32x4  __attribute__((ext_vector_type(4)));
typedef short  bf16x8 __attribute__((ext_vector_type(8)));

static __device__ __forceinline__ ushort f2bf(float f) {
  union { float f; unsigned u; } v; v.f = f;
  unsigned r = v.u + 0x7FFFu + ((v.u >> 16) & 1u);
  return (ushort)(r >> 16);
}

// async global->LDS, 16B per lane; LDS dest is wave-uniform base + lane*16
static __device__ __forceinline__ void gload16(const void* g, void* l) {
  __builtin_amdgcn_global_load_lds((const __attribute__((address_space(1))) void*)g,
                                   (__attribute__((address_space(3))) void*)l, 16, 0, 0);
}

// transpose + fp32->bf16 cast body: in (E,R,C) f32 -> out (E,C,R) bf16
static __device__ __forceinline__ void transpose_body(
    const float* __restrict__ in, ushort* __restrict__ out, int R, int C,
    int bx, int by, int e, float tile[64][65], int t) {
  int r0 = by * 64, c0 = bx * 64;
  int row = t >> 2, seg = t & 3;
  const float* src = in + ((size_t)e * R + r0 + row) * C + c0 + seg * 16;
#pragma unroll
  for (int i = 0; i < 4; ++i) {
    float4 v = *(const float4*)(src + i * 4);
    tile[row][seg * 16 + i * 4 + 0] = v.x;
    tile[row][seg * 16 + i * 4 + 1] = v.y;
    tile[row][seg * 16 + i * 4 + 2] = v.z;
    tile[row][seg * 16 + i * 4 + 3] = v.w;
  }
  __syncthreads();
  int c = t >> 2;
  ushort vals[16];
#pragma unroll
  for (int j = 0; j < 16; ++j) vals[j] = f2bf(tile[seg * 16 + j][c]);
  ushort* dst = out + ((size_t)e * C + c0 + c) * R + r0 + seg * 16;
  *(uint4*)(dst)     = *(uint4*)&vals[0];
  *(uint4*)(dst + 8) = *(uint4*)&vals[8];
}

// ---------------- PREP: one dispatch = zero(out) + route_cast + transpose(w1) + transpose(w2)
__global__ void prep_kernel(const float* __restrict__ x, const float* __restrict__ gw,
                            const float* __restrict__ w1, const float* __restrict__ w2,
                            ushort* __restrict__ xb, float* __restrict__ slotw,
                            int* __restrict__ slote, ushort* __restrict__ w1t,
                            ushort* __restrict__ w2t, float* __restrict__ out) {
  __shared__ float tile[64][65];
  int bid = blockIdx.x;
  int tid = threadIdx.x;
  if (bid < 2048) {
    // ---- route + x-cast (wave per token)
    int tokn = bid * 4 + (tid >> 6);
    int lane = tid & 63;
    const float4* xr = (const float4*)(x + (size_t)tokn * H_ + lane * 8);
    float4 x0 = xr[0], x1 = xr[1];
    ushort v[8] = {f2bf(x0.x), f2bf(x0.y), f2bf(x0.z), f2bf(x0.w),
                   f2bf(x1.x), f2bf(x1.y), f2bf(x1.z), f2bf(x1.w)};
    *(uint4*)(xb + (size_t)tokn * H_ + lane * 8) = *(uint4*)v;
    float acc[E_];
#pragma unroll
    for (int e = 0; e < E_; ++e) {
      const float4* gr = (const float4*)(gw + e * H_ + lane * 8);
      float4 g0 = gr[0], g1 = gr[1];
      acc[e] = x0.x*g0.x + x0.y*g0.y + x0.z*g0.z + x0.w*g0.w
             + x1.x*g1.x + x1.y*g1.y + x1.z*g1.z + x1.w*g1.w;
    }
#pragma unroll
    for (int e = 0; e < E_; ++e) {
#pragma unroll
      for (int off = 32; off; off >>= 1)
        acc[e] += __shfl_xor(acc[e], off);
    }
    if (lane == 0) {
      float v1 = -1e30f, v2 = -1e30f; int i1 = 0, i2 = 0;
#pragma unroll
      for (int e = 0; e < E_; ++e) {
        float vv = acc[e];
        if (vv > v1)      { v2 = v1; i2 = i1; v1 = vv; i1 = e; }
        else if (vv > v2) { v2 = vv; i2 = e; }
      }
      float ex = expf(v2 - v1);
      float inv = 1.0f / (1.0f + ex);
      slote[2 * tokn] = i1;     slotw[2 * tokn] = inv;
      slote[2 * tokn + 1] = i2; slotw[2 * tokn + 1] = ex * inv;
    }
  } else if (bid < 4096) {
    // ---- zero out (replaces hipMemsetAsync)
    float* p = out + (size_t)(bid - 2048) * 2048 + tid * 8;
    float4 z = {0.f, 0.f, 0.f, 0.f};
    *(float4*)(p) = z;
    *(float4*)(p + 4) = z;
  } else if (bid < 6144) {
    int blk = bid - 4096;
    int bx = blk & 31, by = (blk >> 5) & 7, e = blk >> 8;
    transpose_body(w1, w1t, H_, DFF_, bx, by, e, tile, tid);
  } else {
    int blk = bid - 6144;
    int bx = blk & 7, by = (blk >> 3) & 31, e = blk >> 8;
    transpose_body(w2, w2t, DFF_, H_, bx, by, e, tile, tid);
  }
}

// ---------------- R2: deterministic stable counting sort of 16384 slots into
// per-expert lists + per-expert exclusive base. Single 1024-thread block, no atomics.
__global__ __launch_bounds__(1024) void listbuild_kernel(
    const int* __restrict__ slote, int* __restrict__ counts, int* __restrict__ ebase,
    int* __restrict__ lslot) {
  int tid = threadIdx.x, lane = tid & 63, wv = tid >> 6;   // 16 waves
  int base = tid * 16;
  int myexp[16];
  unsigned char cnt[E_] = {0, 0, 0, 0, 0, 0, 0, 0};
#pragma unroll
  for (int i = 0; i < 16; ++i) {
    int e = slote[base + i];
    myexp[i] = e;
    cnt[e]++;
  }
  unsigned long long lo = 0, hi = 0;
#pragma unroll
  for (int e = 0; e < 4; ++e) {
    lo |= (unsigned long long)cnt[e] << (16 * e);
    hi |= (unsigned long long)cnt[e + 4] << (16 * e);
  }
  unsigned long long mylo = lo, myhi = hi;
#pragma unroll
  for (int off = 1; off < 64; off <<= 1) {
    unsigned long long tl = __shfl_up(lo, off);
    unsigned long long th = __shfl_up(hi, off);
    if (lane >= off) { lo += tl; hi += th; }
  }
  __shared__ unsigned long long wtotlo[16], wtothi[16];
  __shared__ unsigned long long wbaselo[16], wbasehi[16];
  if (lane == 63) { wtotlo[wv] = lo; wtothi[wv] = hi; }
  __syncthreads();
  if (tid == 0) {
    unsigned long long rl = 0, rh = 0;
#pragma unroll
    for (int w2 = 0; w2 < 16; ++w2) {
      wbaselo[w2] = rl; wbasehi[w2] = rh;
      rl += wtotlo[w2]; rh += wtothi[w2];
    }
    int run = 0;
#pragma unroll
    for (int e = 0; e < 4; ++e) {
      int tot = (int)((rl >> (16 * e)) & 0xFFFF);
      counts[e] = tot; ebase[e] = run; run += tot;
    }
#pragma unroll
    for (int e = 0; e < 4; ++e) {
      int tot = (int)((rh >> (16 * e)) & 0xFFFF);
      counts[e + 4] = tot; ebase[e + 4] = run; run += tot;
    }
  }
  __syncthreads();
  unsigned long long exlo = wbaselo[wv] + lo - mylo;
  unsigned long long exhi = wbasehi[wv] + hi - myhi;
  int pos[E_];
#pragma unroll
  for (int e = 0; e < 4; ++e) {
    pos[e]     = (int)((exlo >> (16 * e)) & 0xFFFF);
    pos[e + 4] = (int)((exhi >> (16 * e)) & 0xFFFF);
  }
#pragma unroll
  for (int i = 0; i < 16; ++i) {
    int e = myexp[i];
    lslot[e * T_ + pos[e]] = base + i;
    pos[e]++;
  }
}

// ---------------- GEMM1: hdn[list-pos, n] = gelu( Xg @ w1 + b1 )
// 64x128 tile, BK=64. A-fragments DIRECT global->register (1-kstep prefetch);
// LDS holds B only (16 KB). B staging/swizzle identical to r13.
__global__ __launch_bounds__(256, 2) void gemm1_kernel(
    const ushort* __restrict__ xb, const ushort* __restrict__ w1t,
    const float* __restrict__ b1, const int* __restrict__ counts,
    const int* __restrict__ ebase, const int* __restrict__ lslot,
    ushort* __restrict__ hdn, int c0, int DC) {
  int bid = blockIdx.x;
  int e = bid & (E_ - 1);
  int nx = DC / 128;
  int bx = (bid >> 3) % nx;
  int by = (bid >> 3) / nx;
  int cnt = counts[e];
  int m0 = by * 64;
  if (m0 >= cnt) return;
  int n0 = c0 + bx * 128;
  int eb = ebase[e];

  __shared__ ushort sB[128 * 64];   // 16 KB (B only)
  int tid = threadIdx.x, lane = tid & 63, wid = tid >> 6;
  int wm = wid >> 1, wn = wid & 1;   // wave tile: 32 rows x 64 cols
  const int* lst = lslot + e * T_;
  const ushort* w1e = w1t + (size_t)e * DFF_ * H_;

  int lrow = lane >> 3;
  int scol = ((lane & 7) ^ lrow) * 8;

  // per-lane A row pointers (2 row-frags of 16)
  const ushort* arow[2];
#pragma unroll
  for (int i = 0; i < 2; ++i) {
    int r = m0 + wm * 32 + i * 16 + (lane & 15);
    if (r > cnt - 1) r = cnt - 1;
    arow[i] = xb + (size_t)(lst[r] >> 1) * H_ + (lane >> 4) * 8;
  }
  const ushort* bsrc[4];
#pragma unroll
  for (int is = 0; is < 4; ++is) {
    int row = (wid * 4 + is) * 8 + lrow;
    bsrc[is] = w1e + (size_t)(n0 + row) * H_ + scol;
  }

  f32x4 acc[2][4];
#pragma unroll
  for (int i = 0; i < 2; ++i)
#pragma unroll
    for (int j = 0; j < 4; ++j) acc[i][j] = (f32x4){0.f, 0.f, 0.f, 0.f};

  // prefetch A-fragments for kstep 0
  bf16x8 afn[2][2];   // [s][i]
#pragma unroll
  for (int s = 0; s < 2; ++s)
#pragma unroll
    for (int i = 0; i < 2; ++i)
      afn[s][i] = *(const bf16x8*)(arow[i] + s * 32);

  for (int k0 = 0; k0 < H_; k0 += 64) {
    __syncthreads();
#pragma unroll
    for (int is = 0; is < 4; ++is)
      gload16(bsrc[is] + k0, &sB[(wid * 4 + is) * 512]);
    bf16x8 afc[2][2];
#pragma unroll
    for (int s = 0; s < 2; ++s)
#pragma unroll
      for (int i = 0; i < 2; ++i) afc[s][i] = afn[s][i];
    if (k0 + 64 < H_) {
#pragma unroll
      for (int s = 0; s < 2; ++s)
#pragma unroll
        for (int i = 0; i < 2; ++i)
          afn[s][i] = *(const bf16x8*)(arow[i] + k0 + 64 + s * 32);
    }
    __syncthreads();   // drains B-DMA and the afn loads together
#pragma unroll
    for (int s = 0; s < 2; ++s) {
      bf16x8 bfr[4];
#pragma unroll
      for (int j = 0; j < 4; ++j) {
        int row = wn * 64 + j * 16 + (lane & 15);
        bfr[j] = *(const bf16x8*)(&sB[row * 64 + (((s * 4 + (lane >> 4)) ^ (row & 7)) * 8)]);
      }
#pragma unroll
      for (int i = 0; i < 2; ++i)
#pragma unroll
        for (int j = 0; j < 4; ++j)
          acc[i][j] = __builtin_amdgcn_mfma_f32_16x16x32_bf16(afc[s][i], bfr[j], acc[i][j], 0, 0, 0);
    }
  }

  // epilogue: bias + tanh-gelu -> bf16 -> hdn[list-pos][col-c0]
  int cl = lane & 15, rg = lane >> 4;
  float b1v[4];
#pragma unroll
  for (int j = 0; j < 4; ++j) b1v[j] = b1[e * DFF_ + n0 + wn * 64 + j * 16 + cl];
#pragma unroll
  for (int i = 0; i < 2; ++i) {
    int rbase = m0 + wm * 32 + i * 16 + rg * 4;
#pragma unroll
    for (int r = 0; r < 4; ++r) {
      int gr = rbase + r;
      if (gr < cnt) {
        ushort* hrow = hdn + (size_t)(eb + gr) * DC + (n0 - c0) + wn * 64 + cl;
#pragma unroll
        for (int j = 0; j < 4; ++j) {
          float v = acc[i][j][r] + b1v[j];
          float t2 = v + 0.044715f * v * v * v;
          float exv = __expf(1.5957691216057308f * t2);
          float th = 1.0f - 2.0f / (exv + 1.0f);
          hrow[j * 16] = f2bf(0.5f * v * (1.0f + th));
        }
      }
    }
  }
}

// ---------------- GEMM2 + fused combine, 64x128 tile, BK=64.
// A (hdn, list-contiguous) DIRECT global->register with 1-kstep prefetch; LDS = B only.
// out[tok] += slotw[slot] * (hdn_list @ w2 + b2[e])   via fp32 atomics
__global__ __launch_bounds__(256, 2) void gemm2_kernel(
    const ushort* __restrict__ hdn, const ushort* __restrict__ w2t,
    const float* __restrict__ b2, const float* __restrict__ slotw,
    const int* __restrict__ counts, const int* __restrict__ ebase,
    const int* __restrict__ lslot, float* __restrict__ out,
    int c0, int DC, int addb) {
  int bid = blockIdx.x;
  int e = bid & (E_ - 1);
  const int nx = H_ / 128;
  int bx = (bid >> 3) % nx;
  int by = (bid >> 3) / nx;
  int cnt = counts[e];
  int m0 = by * 64;
  if (m0 >= cnt) return;
  int n0 = bx * 128;
  int eb = ebase[e];

  __shared__ ushort sB[128 * 64];   // 16 KB (B only)
  int tid = threadIdx.x, lane = tid & 63, wid = tid >> 6;
  int wm = wid >> 1, wn = wid & 1;   // wave tile: 32 rows x 64 cols
  const int* lst = lslot + e * T_;
  const ushort* w2e = w2t + (size_t)e * H_ * DFF_ + c0;

  int lrow = lane >> 3;
  int scol = ((lane & 7) ^ lrow) * 8;

  const ushort* arow[2];
#pragma unroll
  for (int i = 0; i < 2; ++i) {
    int r = m0 + wm * 32 + i * 16 + (lane & 15);
    if (r > cnt - 1) r = cnt - 1;
    arow[i] = hdn + (size_t)(eb + r) * DC + (lane >> 4) * 8;
  }
  const ushort* bsrc[4];
#pragma unroll
  for (int is = 0; is < 4; ++is) {
    int row = (wid * 4 + is) * 8 + lrow;
    bsrc[is] = w2e + (size_t)(n0 + row) * DFF_ + scol;
  }

  f32x4 acc[2][4];
#pragma unroll
  for (int i = 0; i < 2; ++i)
#pragma unroll
    for (int j = 0; j < 4; ++j) acc[i][j] = (f32x4){0.f, 0.f, 0.f, 0.f};

  bf16x8 afn[2][2];
#pragma unroll
  for (int s = 0; s < 2; ++s)
#pragma unroll
    for (int i = 0; i < 2; ++i)
      afn[s][i] = *(const bf16x8*)(arow[i] + s * 32);

  for (int k0 = 0; k0 < DC; k0 += 64) {
    __syncthreads();
#pragma unroll
    for (int is = 0; is < 4; ++is)
      gload16(bsrc[is] + k0, &sB[(wid * 4 + is) * 512]);
    bf16x8 afc[2][2];
#pragma unroll
    for (int s = 0; s < 2; ++s)
#pragma unroll
      for (int i = 0; i < 2; ++i) afc[s][i] = afn[s][i];
    if (k0 + 64 < DC) {
#pragma unroll
      for (int s = 0; s < 2; ++s)
#pragma unroll
        for (int i = 0; i < 2; ++i)
          afn[s][i] = *(const bf16x8*)(arow[i] + k0 + 64 + s * 32);
    }
    __syncthreads();
#pragma unroll
    for (int s = 0; s < 2; ++s) {
      bf16x8 bfr[4];
#pragma unroll
      for (int j = 0; j < 4; ++j) {
        int row = wn * 64 + j * 16 + (lane & 15);
        bfr[j] = *(const bf16x8*)(&sB[row * 64 + (((s * 4 + (lane >> 4)) ^ (row & 7)) * 8)]);
      }
#pragma unroll
      for (int i = 0; i < 2; ++i)
#pragma unroll
        for (int j = 0; j < 4; ++j)
          acc[i][j] = __builtin_amdgcn_mfma_f32_16x16x32_bf16(afc[s][i], bfr[j], acc[i][j], 0, 0, 0);
    }
  }

  int cl = lane & 15, rg = lane >> 4;
  float b2v[4];
#pragma unroll
  for (int j = 0; j < 4; ++j)
    b2v[j] = addb ? b2[e * H_ + n0 + wn * 64 + j * 16 + cl] : 0.0f;
#pragma unroll
  for (int i = 0; i < 2; ++i) {
    int rbase = m0 + wm * 32 + i * 16 + rg * 4;
#pragma unroll
    for (int r = 0; r < 4; ++r) {
      int gr = rbase + r;
      if (gr < cnt) {
        int slot = lst[gr];
        float wgt = slotw[slot];
        float* orow = out + (size_t)(slot >> 1) * H_ + n0 + wn * 64 + cl;
#pragma unroll
        for (int j = 0; j < 4; ++j)
          atomicAdd(&orow[j * 16], wgt * (acc[i][j][r] + b2v[j]));
      }
    }
  }
}

extern "C" void kernel_launch(void* const* d_in, const int* in_sizes, int n_in,
                              void* d_out, int out_size, void* d_ws, size_t ws_size,
                              hipStream_t stream) {
  const float* x  = (const float*)d_in[0];
  const float* gw = (const float*)d_in[1];
  const float* w1 = (const float*)d_in[2];
  const float* b1 = (const float*)d_in[3];
  const float* w2 = (const float*)d_in[4];
  const float* b2 = (const float*)d_in[5];
  float* out = (float*)d_out;

  char* ws = (char*)d_ws;
  size_t off = 0;
  auto alloc = [&](size_t bytes) -> void* {
    void* p = ws + off; off += (bytes + 255) & ~(size_t)255; return p;
  };
  int*    counts = (int*)alloc(256);
  int*    ebase  = (int*)alloc(256);
  int*    lslot  = (int*)alloc((size_t)E_ * T_ * 4);
  float*  slotw  = (float*)alloc((size_t)NSLOT * 4);
  int*    slote  = (int*)alloc((size_t)NSLOT * 4);
  ushort* w1t    = (ushort*)alloc((size_t)E_ * DFF_ * H_ * 2);
  ushort* w2t    = (ushort*)alloc((size_t)E_ * H_ * DFF_ * 2);
  ushort* xb     = (ushort*)alloc((size_t)T_ * H_ * 2);

  int NC = 1;   // DFF chunking factor, only >1 if ws is tight
  while (NC < 16 && off + (size_t)NSLOT * (DFF_ / NC) * 2 > ws_size) NC *= 2;
  int DC = DFF_ / NC;
  ushort* hdn = (ushort*)alloc((size_t)NSLOT * DC * 2);

  prep_kernel<<<8192, 256, 0, stream>>>(x, gw, w1, w2, xb, slotw, slote, w1t, w2t, out);
  listbuild_kernel<<<1, 1024, 0, stream>>>(slote, counts, ebase, lslot);

  for (int c = 0; c < NC; ++c) {
    gemm1_kernel<<<E_ * (DC / 128) * (T_ / 64), 256, 0, stream>>>(
        xb, w1t, b1, counts, ebase, lslot, hdn, c * DC, DC);
    gemm2_kernel<<<E_ * (H_ / 128) * (T_ / 64), 256, 0, stream>>>(
        hdn, w2t, b2, slotw, counts, ebase, lslot, out, c * DC, DC, c == NC - 1);
  }
}

// Round 15
// 165.224 us; speedup vs baseline: 1.4238x; 1.4238x over previous
//
#include <hip/hip_runtime.h>
#include <hip/hip_bf16.h>

#define E_    8
#define H_    512
#define DFF_  2048
#define T_    8192
#define NSLOT (2 * T_)

typedef float  f32x4  __attribute__((ext_vector_type(4)));
typedef short  bf16x8 __attribute__((ext_vector_type(8)));

static __device__ __forceinline__ ushort f2bf(float f) {
  union { float f; unsigned u; } v; v.f = f;
  unsigned r = v.u + 0x7FFFu + ((v.u >> 16) & 1u);
  return (ushort)(r >> 16);
}

// async global->LDS, 16B per lane; LDS dest is wave-uniform base + lane*16
static __device__ __forceinline__ void gload16(const void* g, void* l) {
  __builtin_amdgcn_global_load_lds((const __attribute__((address_space(1))) void*)g,
                                   (__attribute__((address_space(3))) void*)l, 16, 0, 0);
}

// transpose + fp32->bf16 cast body: in (E,R,C) f32 -> out (E,C,R) bf16
static __device__ __forceinline__ void transpose_body(
    const float* __restrict__ in, ushort* __restrict__ out, int R, int C,
    int bx, int by, int e, float tile[64][65], int t) {
  int r0 = by * 64, c0 = bx * 64;
  int row = t >> 2, seg = t & 3;
  const float* src = in + ((size_t)e * R + r0 + row) * C + c0 + seg * 16;
#pragma unroll
  for (int i = 0; i < 4; ++i) {
    float4 v = *(const float4*)(src + i * 4);
    tile[row][seg * 16 + i * 4 + 0] = v.x;
    tile[row][seg * 16 + i * 4 + 1] = v.y;
    tile[row][seg * 16 + i * 4 + 2] = v.z;
    tile[row][seg * 16 + i * 4 + 3] = v.w;
  }
  __syncthreads();
  int c = t >> 2;
  ushort vals[16];
#pragma unroll
  for (int j = 0; j < 16; ++j) vals[j] = f2bf(tile[seg * 16 + j][c]);
  ushort* dst = out + ((size_t)e * C + c0 + c) * R + r0 + seg * 16;
  *(uint4*)(dst)     = *(uint4*)&vals[0];
  *(uint4*)(dst + 8) = *(uint4*)&vals[8];
}

// ---------------- PREP: one dispatch = zero(out) + route_cast + transpose(w1) + transpose(w2)
__global__ void prep_kernel(const float* __restrict__ x, const float* __restrict__ gw,
                            const float* __restrict__ w1, const float* __restrict__ w2,
                            ushort* __restrict__ xb, float* __restrict__ slotw,
                            int* __restrict__ slote, ushort* __restrict__ w1t,
                            ushort* __restrict__ w2t, float* __restrict__ out) {
  __shared__ float tile[64][65];
  int bid = blockIdx.x;
  int tid = threadIdx.x;
  if (bid < 2048) {
    // ---- route + x-cast (wave per token)
    int tokn = bid * 4 + (tid >> 6);
    int lane = tid & 63;
    const float4* xr = (const float4*)(x + (size_t)tokn * H_ + lane * 8);
    float4 x0 = xr[0], x1 = xr[1];
    ushort v[8] = {f2bf(x0.x), f2bf(x0.y), f2bf(x0.z), f2bf(x0.w),
                   f2bf(x1.x), f2bf(x1.y), f2bf(x1.z), f2bf(x1.w)};
    *(uint4*)(xb + (size_t)tokn * H_ + lane * 8) = *(uint4*)v;
    float acc[E_];
#pragma unroll
    for (int e = 0; e < E_; ++e) {
      const float4* gr = (const float4*)(gw + e * H_ + lane * 8);
      float4 g0 = gr[0], g1 = gr[1];
      acc[e] = x0.x*g0.x + x0.y*g0.y + x0.z*g0.z + x0.w*g0.w
             + x1.x*g1.x + x1.y*g1.y + x1.z*g1.z + x1.w*g1.w;
    }
#pragma unroll
    for (int e = 0; e < E_; ++e) {
#pragma unroll
      for (int off = 32; off; off >>= 1)
        acc[e] += __shfl_xor(acc[e], off);
    }
    if (lane == 0) {
      float v1 = -1e30f, v2 = -1e30f; int i1 = 0, i2 = 0;
#pragma unroll
      for (int e = 0; e < E_; ++e) {
        float vv = acc[e];
        if (vv > v1)      { v2 = v1; i2 = i1; v1 = vv; i1 = e; }
        else if (vv > v2) { v2 = vv; i2 = e; }
      }
      float ex = expf(v2 - v1);
      float inv = 1.0f / (1.0f + ex);
      slote[2 * tokn] = i1;     slotw[2 * tokn] = inv;
      slote[2 * tokn + 1] = i2; slotw[2 * tokn + 1] = ex * inv;
    }
  } else if (bid < 4096) {
    // ---- zero out (replaces hipMemsetAsync)
    float* p = out + (size_t)(bid - 2048) * 2048 + tid * 8;
    float4 z = {0.f, 0.f, 0.f, 0.f};
    *(float4*)(p) = z;
    *(float4*)(p + 4) = z;
  } else if (bid < 6144) {
    int blk = bid - 4096;
    int bx = blk & 31, by = (blk >> 5) & 7, e = blk >> 8;
    transpose_body(w1, w1t, H_, DFF_, bx, by, e, tile, tid);
  } else {
    int blk = bid - 6144;
    int bx = blk & 7, by = (blk >> 3) & 31, e = blk >> 8;
    transpose_body(w2, w2t, DFF_, H_, bx, by, e, tile, tid);
  }
}

// ---------------- R2: deterministic stable counting sort of 16384 slots into
// per-expert lists + per-expert exclusive base. Single 1024-thread block, no atomics.
__global__ __launch_bounds__(1024) void listbuild_kernel(
    const int* __restrict__ slote, int* __restrict__ counts, int* __restrict__ ebase,
    int* __restrict__ lslot) {
  int tid = threadIdx.x, lane = tid & 63, wv = tid >> 6;   // 16 waves
  int base = tid * 16;
  int myexp[16];
  unsigned char cnt[E_] = {0, 0, 0, 0, 0, 0, 0, 0};
#pragma unroll
  for (int i = 0; i < 16; ++i) {
    int e = slote[base + i];
    myexp[i] = e;
    cnt[e]++;
  }
  unsigned long long lo = 0, hi = 0;
#pragma unroll
  for (int e = 0; e < 4; ++e) {
    lo |= (unsigned long long)cnt[e] << (16 * e);
    hi |= (unsigned long long)cnt[e + 4] << (16 * e);
  }
  unsigned long long mylo = lo, myhi = hi;
#pragma unroll
  for (int off = 1; off < 64; off <<= 1) {
    unsigned long long tl = __shfl_up(lo, off);
    unsigned long long th = __shfl_up(hi, off);
    if (lane >= off) { lo += tl; hi += th; }
  }
  __shared__ unsigned long long wtotlo[16], wtothi[16];
  __shared__ unsigned long long wbaselo[16], wbasehi[16];
  if (lane == 63) { wtotlo[wv] = lo; wtothi[wv] = hi; }
  __syncthreads();
  if (tid == 0) {
    unsigned long long rl = 0, rh = 0;
#pragma unroll
    for (int w2 = 0; w2 < 16; ++w2) {
      wbaselo[w2] = rl; wbasehi[w2] = rh;
      rl += wtotlo[w2]; rh += wtothi[w2];
    }
    int run = 0;
#pragma unroll
    for (int e = 0; e < 4; ++e) {
      int tot = (int)((rl >> (16 * e)) & 0xFFFF);
      counts[e] = tot; ebase[e] = run; run += tot;
    }
#pragma unroll
    for (int e = 0; e < 4; ++e) {
      int tot = (int)((rh >> (16 * e)) & 0xFFFF);
      counts[e + 4] = tot; ebase[e + 4] = run; run += tot;
    }
  }
  __syncthreads();
  unsigned long long exlo = wbaselo[wv] + lo - mylo;
  unsigned long long exhi = wbasehi[wv] + hi - myhi;
  int pos[E_];
#pragma unroll
  for (int e = 0; e < 4; ++e) {
    pos[e]     = (int)((exlo >> (16 * e)) & 0xFFFF);
    pos[e + 4] = (int)((exhi >> (16 * e)) & 0xFFFF);
  }
#pragma unroll
  for (int i = 0; i < 16; ++i) {
    int e = myexp[i];
    lslot[e * T_ + pos[e]] = base + i;
    pos[e]++;
  }
}

// ---------------- GEMM1: hdn[list-pos, n] = gelu( Xg @ w1 + b1 )
// 4x(64)x128 tiles per block, BK=64 serial. B panel staged ONCE per K-step
// for 4 A-tiles (12 KB staged/tile vs 24); B LDS fragments reused across tiles.
__global__ __launch_bounds__(256, 2) void gemm1_kernel(
    const ushort* __restrict__ xb, const ushort* __restrict__ w1t,
    const float* __restrict__ b1, const int* __restrict__ counts,
    const int* __restrict__ ebase, const int* __restrict__ lslot,
    ushort* __restrict__ hdn, int c0, int DC) {
  int bid = blockIdx.x;
  int e = bid & (E_ - 1);
  int nx = DC / 128;
  int bx = (bid >> 3) % nx;
  int bg = (bid >> 3) / nx;
  int cnt = counts[e];
  int m0g = bg * 256;
  if (m0g >= cnt) return;
  int n0 = c0 + bx * 128;
  int eb = ebase[e];

  __shared__ ushort sA[4][64 * 64];   // 32 KB
  __shared__ ushort sB[128 * 64];     // 16 KB
  int tid = threadIdx.x, lane = tid & 63, wid = tid >> 6;
  int wm = wid >> 1, wn = wid & 1;    // wave tile: 32 rows x 64 cols per sub-tile
  const int* lst = lslot + e * T_;
  const ushort* w1e = w1t + (size_t)e * DFF_ * H_;

  int lrow = lane >> 3;
  int scol = ((lane & 7) ^ lrow) * 8;

  const ushort* asrc[4][2]; const ushort* bsrc[4];
#pragma unroll
  for (int t = 0; t < 4; ++t)
#pragma unroll
    for (int is = 0; is < 2; ++is) {
      int row = (wid * 2 + is) * 8 + lrow;
      int r = m0g + t * 64 + row; if (r > cnt - 1) r = cnt - 1;
      asrc[t][is] = xb + (size_t)(lst[r] >> 1) * H_ + scol;
    }
#pragma unroll
  for (int is = 0; is < 4; ++is) {
    int row = (wid * 4 + is) * 8 + lrow;
    bsrc[is] = w1e + (size_t)(n0 + row) * H_ + scol;
  }

  f32x4 acc[4][2][4];
#pragma unroll
  for (int t = 0; t < 4; ++t)
#pragma unroll
    for (int i = 0; i < 2; ++i)
#pragma unroll
      for (int j = 0; j < 4; ++j) acc[t][i][j] = (f32x4){0.f, 0.f, 0.f, 0.f};

  for (int k0 = 0; k0 < H_; k0 += 64) {
    __syncthreads();
#pragma unroll
    for (int t = 0; t < 4; ++t)
#pragma unroll
      for (int is = 0; is < 2; ++is)
        gload16(asrc[t][is] + k0, &sA[t][(wid * 2 + is) * 512]);
#pragma unroll
    for (int is = 0; is < 4; ++is)
      gload16(bsrc[is] + k0, &sB[(wid * 4 + is) * 512]);
    __syncthreads();
#pragma unroll
    for (int s = 0; s < 2; ++s) {
      bf16x8 bfr[4];
#pragma unroll
      for (int j = 0; j < 4; ++j) {
        int row = wn * 64 + j * 16 + (lane & 15);
        bfr[j] = *(const bf16x8*)(&sB[row * 64 + (((s * 4 + (lane >> 4)) ^ (row & 7)) * 8)]);
      }
#pragma unroll
      for (int t = 0; t < 4; ++t) {
        bf16x8 af[2];
#pragma unroll
        for (int i = 0; i < 2; ++i) {
          int row = wm * 32 + i * 16 + (lane & 15);
          af[i] = *(const bf16x8*)(&sA[t][row * 64 + (((s * 4 + (lane >> 4)) ^ (row & 7)) * 8)]);
        }
#pragma unroll
        for (int i = 0; i < 2; ++i)
#pragma unroll
          for (int j = 0; j < 4; ++j)
            acc[t][i][j] = __builtin_amdgcn_mfma_f32_16x16x32_bf16(af[i], bfr[j], acc[t][i][j], 0, 0, 0);
      }
    }
  }

  // epilogue: bias + tanh-gelu -> bf16 -> hdn[list-pos][col-c0]
  int cl = lane & 15, rg = lane >> 4;
  float b1v[4];
#pragma unroll
  for (int j = 0; j < 4; ++j) b1v[j] = b1[e * DFF_ + n0 + wn * 64 + j * 16 + cl];
#pragma unroll
  for (int t = 0; t < 4; ++t)
#pragma unroll
    for (int i = 0; i < 2; ++i) {
      int rbase = m0g + t * 64 + wm * 32 + i * 16 + rg * 4;
#pragma unroll
      for (int r = 0; r < 4; ++r) {
        int gr = rbase + r;
        if (gr < cnt) {
          ushort* hrow = hdn + (size_t)(eb + gr) * DC + (n0 - c0) + wn * 64 + cl;
#pragma unroll
          for (int j = 0; j < 4; ++j) {
            float v = acc[t][i][j][r] + b1v[j];
            float t2 = v + 0.044715f * v * v * v;
            float exv = __expf(1.5957691216057308f * t2);
            float th = 1.0f - 2.0f / (exv + 1.0f);
            hrow[j * 16] = f2bf(0.5f * v * (1.0f + th));
          }
        }
      }
    }
}

// ---------------- GEMM2 + fused combine: 2x(64)x128 tiles per block, BK=64 serial.
// B panel staged once per K-step for 2 A-tiles (16 KB staged/tile vs 24).
// out[tok] += slotw[slot] * (hdn_list @ w2 + b2[e])   via fp32 atomics
__global__ __launch_bounds__(256, 2) void gemm2_kernel(
    const ushort* __restrict__ hdn, const ushort* __restrict__ w2t,
    const float* __restrict__ b2, const float* __restrict__ slotw,
    const int* __restrict__ counts, const int* __restrict__ ebase,
    const int* __restrict__ lslot, float* __restrict__ out,
    int c0, int DC, int addb) {
  int bid = blockIdx.x;
  int e = bid & (E_ - 1);
  const int nx = H_ / 128;
  int bx = (bid >> 3) % nx;
  int bg = (bid >> 3) / nx;
  int cnt = counts[e];
  int m0g = bg * 128;
  if (m0g >= cnt) return;
  int n0 = bx * 128;
  int eb = ebase[e];

  __shared__ ushort sA[2][64 * 64];   // 16 KB
  __shared__ ushort sB[128 * 64];     // 16 KB
  int tid = threadIdx.x, lane = tid & 63, wid = tid >> 6;
  int wm = wid >> 1, wn = wid & 1;    // wave tile: 32 rows x 64 cols per sub-tile
  const int* lst = lslot + e * T_;
  const ushort* w2e = w2t + (size_t)e * H_ * DFF_ + c0;

  int lrow = lane >> 3;
  int scol = ((lane & 7) ^ lrow) * 8;

  const ushort* asrc[2][2]; const ushort* bsrc[4];
#pragma unroll
  for (int t = 0; t < 2; ++t)
#pragma unroll
    for (int is = 0; is < 2; ++is) {
      int row = (wid * 2 + is) * 8 + lrow;
      int r = m0g + t * 64 + row; if (r > cnt - 1) r = cnt - 1;
      asrc[t][is] = hdn + (size_t)(eb + r) * DC + scol;
    }
#pragma unroll
  for (int is = 0; is < 4; ++is) {
    int row = (wid * 4 + is) * 8 + lrow;
    bsrc[is] = w2e + (size_t)(n0 + row) * DFF_ + scol;
  }

  f32x4 acc[2][2][4];
#pragma unroll
  for (int t = 0; t < 2; ++t)
#pragma unroll
    for (int i = 0; i < 2; ++i)
#pragma unroll
      for (int j = 0; j < 4; ++j) acc[t][i][j] = (f32x4){0.f, 0.f, 0.f, 0.f};

  for (int k0 = 0; k0 < DC; k0 += 64) {
    __syncthreads();
#pragma unroll
    for (int t = 0; t < 2; ++t)
#pragma unroll
      for (int is = 0; is < 2; ++is)
        gload16(asrc[t][is] + k0, &sA[t][(wid * 2 + is) * 512]);
#pragma unroll
    for (int is = 0; is < 4; ++is)
      gload16(bsrc[is] + k0, &sB[(wid * 4 + is) * 512]);
    __syncthreads();
#pragma unroll
    for (int s = 0; s < 2; ++s) {
      bf16x8 bfr[4];
#pragma unroll
      for (int j = 0; j < 4; ++j) {
        int row = wn * 64 + j * 16 + (lane & 15);
        bfr[j] = *(const bf16x8*)(&sB[row * 64 + (((s * 4 + (lane >> 4)) ^ (row & 7)) * 8)]);
      }
#pragma unroll
      for (int t = 0; t < 2; ++t) {
        bf16x8 af[2];
#pragma unroll
        for (int i = 0; i < 2; ++i) {
          int row = wm * 32 + i * 16 + (lane & 15);
          af[i] = *(const bf16x8*)(&sA[t][row * 64 + (((s * 4 + (lane >> 4)) ^ (row & 7)) * 8)]);
        }
#pragma unroll
        for (int i = 0; i < 2; ++i)
#pragma unroll
          for (int j = 0; j < 4; ++j)
            acc[t][i][j] = __builtin_amdgcn_mfma_f32_16x16x32_bf16(af[i], bfr[j], acc[t][i][j], 0, 0, 0);
      }
    }
  }

  int cl = lane & 15, rg = lane >> 4;
  float b2v[4];
#pragma unroll
  for (int j = 0; j < 4; ++j)
    b2v[j] = addb ? b2[e * H_ + n0 + wn * 64 + j * 16 + cl] : 0.0f;
#pragma unroll
  for (int t = 0; t < 2; ++t)
#pragma unroll
    for (int i = 0; i < 2; ++i) {
      int rbase = m0g + t * 64 + wm * 32 + i * 16 + rg * 4;
#pragma unroll
      for (int r = 0; r < 4; ++r) {
        int gr = rbase + r;
        if (gr < cnt) {
          int slot = lst[gr];
          float wgt = slotw[slot];
          float* orow = out + (size_t)(slot >> 1) * H_ + n0 + wn * 64 + cl;
#pragma unroll
          for (int j = 0; j < 4; ++j)
            atomicAdd(&orow[j * 16], wgt * (acc[t][i][j][r] + b2v[j]));
        }
      }
    }
}

extern "C" void kernel_launch(void* const* d_in, const int* in_sizes, int n_in,
                              void* d_out, int out_size, void* d_ws, size_t ws_size,
                              hipStream_t stream) {
  const float* x  = (const float*)d_in[0];
  const float* gw = (const float*)d_in[1];
  const float* w1 = (const float*)d_in[2];
  const float* b1 = (const float*)d_in[3];
  const float* w2 = (const float*)d_in[4];
  const float* b2 = (const float*)d_in[5];
  float* out = (float*)d_out;

  char* ws = (char*)d_ws;
  size_t off = 0;
  auto alloc = [&](size_t bytes) -> void* {
    void* p = ws + off; off += (bytes + 255) & ~(size_t)255; return p;
  };
  int*    counts = (int*)alloc(256);
  int*    ebase  = (int*)alloc(256);
  int*    lslot  = (int*)alloc((size_t)E_ * T_ * 4);
  float*  slotw  = (float*)alloc((size_t)NSLOT * 4);
  int*    slote  = (int*)alloc((size_t)NSLOT * 4);
  ushort* w1t    = (ushort*)alloc((size_t)E_ * DFF_ * H_ * 2);
  ushort* w2t    = (ushort*)alloc((size_t)E_ * H_ * DFF_ * 2);
  ushort* xb     = (ushort*)alloc((size_t)T_ * H_ * 2);

  int NC = 1;   // DFF chunking factor, only >1 if ws is tight
  while (NC < 16 && off + (size_t)NSLOT * (DFF_ / NC) * 2 > ws_size) NC *= 2;
  int DC = DFF_ / NC;
  ushort* hdn = (ushort*)alloc((size_t)NSLOT * DC * 2);

  prep_kernel<<<8192, 256, 0, stream>>>(x, gw, w1, w2, xb, slotw, slote, w1t, w2t, out);
  listbuild_kernel<<<1, 1024, 0, stream>>>(slote, counts, ebase, lslot);

  for (int c = 0; c < NC; ++c) {
    gemm1_kernel<<<E_ * (DC / 128) * (T_ / 256), 256, 0, stream>>>(
        xb, w1t, b1, counts, ebase, lslot, hdn, c * DC, DC);
    gemm2_kernel<<<E_ * (H_ / 128) * (T_ / 128), 256, 0, stream>>>(
        hdn, w2t, b2, slotw, counts, ebase, lslot, out, c * DC, DC, c == NC - 1);
  }
}

// Round 16
// 154.991 us; speedup vs baseline: 1.5178x; 1.0660x over previous
//
#include <hip/hip_runtime.h>
#include <hip/hip_bf16.h>

#define E_    8
#define H_    512
#define DFF_  2048
#define T_    8192
#define NSLOT (2 * T_)

typedef float  f32x4  __attribute__((ext_vector_type(4)));
typedef short  bf16x8 __attribute__((ext_vector_type(8)));

static __device__ __forceinline__ ushort f2bf(float f) {
  union { float f; unsigned u; } v; v.f = f;
  unsigned r = v.u + 0x7FFFu + ((v.u >> 16) & 1u);
  return (ushort)(r >> 16);
}

// async global->LDS, 16B per lane; LDS dest is wave-uniform base + lane*16
static __device__ __forceinline__ void gload16(const void* g, void* l) {
  __builtin_amdgcn_global_load_lds((const __attribute__((address_space(1))) void*)g,
                                   (__attribute__((address_space(3))) void*)l, 16, 0, 0);
}

// transpose + fp32->bf16 cast body: in (E,R,C) f32 -> out (E,C,R) bf16
static __device__ __forceinline__ void transpose_body(
    const float* __restrict__ in, ushort* __restrict__ out, int R, int C,
    int bx, int by, int e, float tile[64][65], int t) {
  int r0 = by * 64, c0 = bx * 64;
  int row = t >> 2, seg = t & 3;
  const float* src = in + ((size_t)e * R + r0 + row) * C + c0 + seg * 16;
#pragma unroll
  for (int i = 0; i < 4; ++i) {
    float4 v = *(const float4*)(src + i * 4);
    tile[row][seg * 16 + i * 4 + 0] = v.x;
    tile[row][seg * 16 + i * 4 + 1] = v.y;
    tile[row][seg * 16 + i * 4 + 2] = v.z;
    tile[row][seg * 16 + i * 4 + 3] = v.w;
  }
  __syncthreads();
  int c = t >> 2;
  ushort vals[16];
#pragma unroll
  for (int j = 0; j < 16; ++j) vals[j] = f2bf(tile[seg * 16 + j][c]);
  ushort* dst = out + ((size_t)e * C + c0 + c) * R + r0 + seg * 16;
  *(uint4*)(dst)     = *(uint4*)&vals[0];
  *(uint4*)(dst + 8) = *(uint4*)&vals[8];
}

// ---------------- PREP: one dispatch = zero(out) + route_cast + transpose(w1) + transpose(w2)
__global__ void prep_kernel(const float* __restrict__ x, const float* __restrict__ gw,
                            const float* __restrict__ w1, const float* __restrict__ w2,
                            ushort* __restrict__ xb, float* __restrict__ slotw,
                            int* __restrict__ slote, ushort* __restrict__ w1t,
                            ushort* __restrict__ w2t, float* __restrict__ out) {
  __shared__ float tile[64][65];
  int bid = blockIdx.x;
  int tid = threadIdx.x;
  if (bid < 2048) {
    // ---- route + x-cast (wave per token)
    int tokn = bid * 4 + (tid >> 6);
    int lane = tid & 63;
    const float4* xr = (const float4*)(x + (size_t)tokn * H_ + lane * 8);
    float4 x0 = xr[0], x1 = xr[1];
    ushort v[8] = {f2bf(x0.x), f2bf(x0.y), f2bf(x0.z), f2bf(x0.w),
                   f2bf(x1.x), f2bf(x1.y), f2bf(x1.z), f2bf(x1.w)};
    *(uint4*)(xb + (size_t)tokn * H_ + lane * 8) = *(uint4*)v;
    float acc[E_];
#pragma unroll
    for (int e = 0; e < E_; ++e) {
      const float4* gr = (const float4*)(gw + e * H_ + lane * 8);
      float4 g0 = gr[0], g1 = gr[1];
      acc[e] = x0.x*g0.x + x0.y*g0.y + x0.z*g0.z + x0.w*g0.w
             + x1.x*g1.x + x1.y*g1.y + x1.z*g1.z + x1.w*g1.w;
    }
#pragma unroll
    for (int e = 0; e < E_; ++e) {
#pragma unroll
      for (int off = 32; off; off >>= 1)
        acc[e] += __shfl_xor(acc[e], off);
    }
    if (lane == 0) {
      float v1 = -1e30f, v2 = -1e30f; int i1 = 0, i2 = 0;
#pragma unroll
      for (int e = 0; e < E_; ++e) {
        float vv = acc[e];
        if (vv > v1)      { v2 = v1; i2 = i1; v1 = vv; i1 = e; }
        else if (vv > v2) { v2 = vv; i2 = e; }
      }
      float ex = expf(v2 - v1);
      float inv = 1.0f / (1.0f + ex);
      slote[2 * tokn] = i1;     slotw[2 * tokn] = inv;
      slote[2 * tokn + 1] = i2; slotw[2 * tokn + 1] = ex * inv;
    }
  } else if (bid < 4096) {
    // ---- zero out (replaces hipMemsetAsync)
    float* p = out + (size_t)(bid - 2048) * 2048 + tid * 8;
    float4 z = {0.f, 0.f, 0.f, 0.f};
    *(float4*)(p) = z;
    *(float4*)(p + 4) = z;
  } else if (bid < 6144) {
    int blk = bid - 4096;
    int bx = blk & 31, by = (blk >> 5) & 7, e = blk >> 8;
    transpose_body(w1, w1t, H_, DFF_, bx, by, e, tile, tid);
  } else {
    int blk = bid - 6144;
    int bx = blk & 7, by = (blk >> 3) & 31, e = blk >> 8;
    transpose_body(w2, w2t, DFF_, H_, bx, by, e, tile, tid);
  }
}

// ---------------- R2: deterministic stable counting sort of 16384 slots into
// per-expert lists + per-expert exclusive base. Single 1024-thread block, no atomics.
__global__ __launch_bounds__(1024) void listbuild_kernel(
    const int* __restrict__ slote, int* __restrict__ counts, int* __restrict__ ebase,
    int* __restrict__ lslot) {
  int tid = threadIdx.x, lane = tid & 63, wv = tid >> 6;   // 16 waves
  int base = tid * 16;
  int myexp[16];
  unsigned char cnt[E_] = {0, 0, 0, 0, 0, 0, 0, 0};
#pragma unroll
  for (int i = 0; i < 16; ++i) {
    int e = slote[base + i];
    myexp[i] = e;
    cnt[e]++;
  }
  unsigned long long lo = 0, hi = 0;
#pragma unroll
  for (int e = 0; e < 4; ++e) {
    lo |= (unsigned long long)cnt[e] << (16 * e);
    hi |= (unsigned long long)cnt[e + 4] << (16 * e);
  }
  unsigned long long mylo = lo, myhi = hi;
#pragma unroll
  for (int off = 1; off < 64; off <<= 1) {
    unsigned long long tl = __shfl_up(lo, off);
    unsigned long long th = __shfl_up(hi, off);
    if (lane >= off) { lo += tl; hi += th; }
  }
  __shared__ unsigned long long wtotlo[16], wtothi[16];
  __shared__ unsigned long long wbaselo[16], wbasehi[16];
  if (lane == 63) { wtotlo[wv] = lo; wtothi[wv] = hi; }
  __syncthreads();
  if (tid == 0) {
    unsigned long long rl = 0, rh = 0;
#pragma unroll
    for (int w2 = 0; w2 < 16; ++w2) {
      wbaselo[w2] = rl; wbasehi[w2] = rh;
      rl += wtotlo[w2]; rh += wtothi[w2];
    }
    int run = 0;
#pragma unroll
    for (int e = 0; e < 4; ++e) {
      int tot = (int)((rl >> (16 * e)) & 0xFFFF);
      counts[e] = tot; ebase[e] = run; run += tot;
    }
#pragma unroll
    for (int e = 0; e < 4; ++e) {
      int tot = (int)((rh >> (16 * e)) & 0xFFFF);
      counts[e + 4] = tot; ebase[e + 4] = run; run += tot;
    }
  }
  __syncthreads();
  unsigned long long exlo = wbaselo[wv] + lo - mylo;
  unsigned long long exhi = wbasehi[wv] + hi - myhi;
  int pos[E_];
#pragma unroll
  for (int e = 0; e < 4; ++e) {
    pos[e]     = (int)((exlo >> (16 * e)) & 0xFFFF);
    pos[e + 4] = (int)((exhi >> (16 * e)) & 0xFFFF);
  }
#pragma unroll
  for (int i = 0; i < 16; ++i) {
    int e = myexp[i];
    lslot[e * T_ + pos[e]] = base + i;
    pos[e]++;
  }
}

// ---------------- GEMM1: hdn[list-pos, n] = gelu( Xg @ w1 + b1 )
// r13 winner: single 64x128 tile, BK=64 serial, 24 KB LDS.
__global__ __launch_bounds__(256, 2) void gemm1_kernel(
    const ushort* __restrict__ xb, const ushort* __restrict__ w1t,
    const float* __restrict__ b1, const int* __restrict__ counts,
    const int* __restrict__ ebase, const int* __restrict__ lslot,
    ushort* __restrict__ hdn, int c0, int DC) {
  int bid = blockIdx.x;
  int e = bid & (E_ - 1);
  int nx = DC / 128;
  int bx = (bid >> 3) % nx;
  int by = (bid >> 3) / nx;
  int cnt = counts[e];
  int m0 = by * 64;
  if (m0 >= cnt) return;
  int n0 = c0 + bx * 128;
  int eb = ebase[e];

  __shared__ ushort sA[64 * 64];    // 8 KB
  __shared__ ushort sB[128 * 64];   // 16 KB
  int tid = threadIdx.x, lane = tid & 63, wid = tid >> 6;
  int wm = wid >> 1, wn = wid & 1;   // wave tile: 32 rows x 64 cols
  const int* lst = lslot + e * T_;
  const ushort* w1e = w1t + (size_t)e * DFF_ * H_;

  int lrow = lane >> 3;
  int scol = ((lane & 7) ^ lrow) * 8;

  const ushort* asrc[2]; const ushort* bsrc[4];
#pragma unroll
  for (int is = 0; is < 2; ++is) {
    int row = (wid * 2 + is) * 8 + lrow;            // 64 A-rows
    int r = m0 + row; if (r > cnt - 1) r = cnt - 1;
    asrc[is] = xb + (size_t)(lst[r] >> 1) * H_ + scol;
  }
#pragma unroll
  for (int is = 0; is < 4; ++is) {
    int row = (wid * 4 + is) * 8 + lrow;            // 128 B-rows
    bsrc[is] = w1e + (size_t)(n0 + row) * H_ + scol;
  }

  f32x4 acc[2][4];
#pragma unroll
  for (int i = 0; i < 2; ++i)
#pragma unroll
    for (int j = 0; j < 4; ++j) acc[i][j] = (f32x4){0.f, 0.f, 0.f, 0.f};

  for (int k0 = 0; k0 < H_; k0 += 64) {
    __syncthreads();
#pragma unroll
    for (int is = 0; is < 2; ++is)
      gload16(asrc[is] + k0, &sA[(wid * 2 + is) * 512]);
#pragma unroll
    for (int is = 0; is < 4; ++is)
      gload16(bsrc[is] + k0, &sB[(wid * 4 + is) * 512]);
    __syncthreads();
#pragma unroll
    for (int s = 0; s < 2; ++s) {
      bf16x8 af[2], bfr[4];
#pragma unroll
      for (int i = 0; i < 2; ++i) {
        int row = wm * 32 + i * 16 + (lane & 15);
        af[i] = *(const bf16x8*)(&sA[row * 64 + (((s * 4 + (lane >> 4)) ^ (row & 7)) * 8)]);
      }
#pragma unroll
      for (int j = 0; j < 4; ++j) {
        int row = wn * 64 + j * 16 + (lane & 15);
        bfr[j] = *(const bf16x8*)(&sB[row * 64 + (((s * 4 + (lane >> 4)) ^ (row & 7)) * 8)]);
      }
#pragma unroll
      for (int i = 0; i < 2; ++i)
#pragma unroll
        for (int j = 0; j < 4; ++j)
          acc[i][j] = __builtin_amdgcn_mfma_f32_16x16x32_bf16(af[i], bfr[j], acc[i][j], 0, 0, 0);
    }
  }

  // epilogue: bias + tanh-gelu -> bf16 -> hdn[list-pos][col-c0]
  int cl = lane & 15, rg = lane >> 4;
  float b1v[4];
#pragma unroll
  for (int j = 0; j < 4; ++j) b1v[j] = b1[e * DFF_ + n0 + wn * 64 + j * 16 + cl];
#pragma unroll
  for (int i = 0; i < 2; ++i) {
    int rbase = m0 + wm * 32 + i * 16 + rg * 4;
#pragma unroll
    for (int r = 0; r < 4; ++r) {
      int gr = rbase + r;
      if (gr < cnt) {
        ushort* hrow = hdn + (size_t)(eb + gr) * DC + (n0 - c0) + wn * 64 + cl;
#pragma unroll
        for (int j = 0; j < 4; ++j) {
          float v = acc[i][j][r] + b1v[j];
          float t2 = v + 0.044715f * v * v * v;
          float exv = __expf(1.5957691216057308f * t2);
          float th = 1.0f - 2.0f / (exv + 1.0f);
          hrow[j * 16] = f2bf(0.5f * v * (1.0f + th));
        }
      }
    }
  }
}

// ---------------- GEMM2 + fused combine: 2x(64)x128 tiles per block, BK=64 serial.
// B panel staged once per K-step for 2 A-tiles (16 KB staged/tile vs 24).
// out[tok] += slotw[slot] * (hdn_list @ w2 + b2[e])   via fp32 atomics
__global__ __launch_bounds__(256, 2) void gemm2_kernel(
    const ushort* __restrict__ hdn, const ushort* __restrict__ w2t,
    const float* __restrict__ b2, const float* __restrict__ slotw,
    const int* __restrict__ counts, const int* __restrict__ ebase,
    const int* __restrict__ lslot, float* __restrict__ out,
    int c0, int DC, int addb) {
  int bid = blockIdx.x;
  int e = bid & (E_ - 1);
  const int nx = H_ / 128;
  int bx = (bid >> 3) % nx;
  int bg = (bid >> 3) / nx;
  int cnt = counts[e];
  int m0g = bg * 128;
  if (m0g >= cnt) return;
  int n0 = bx * 128;
  int eb = ebase[e];

  __shared__ ushort sA[2][64 * 64];   // 16 KB
  __shared__ ushort sB[128 * 64];     // 16 KB
  int tid = threadIdx.x, lane = tid & 63, wid = tid >> 6;
  int wm = wid >> 1, wn = wid & 1;    // wave tile: 32 rows x 64 cols per sub-tile
  const int* lst = lslot + e * T_;
  const ushort* w2e = w2t + (size_t)e * H_ * DFF_ + c0;

  int lrow = lane >> 3;
  int scol = ((lane & 7) ^ lrow) * 8;

  const ushort* asrc[2][2]; const ushort* bsrc[4];
#pragma unroll
  for (int t = 0; t < 2; ++t)
#pragma unroll
    for (int is = 0; is < 2; ++is) {
      int row = (wid * 2 + is) * 8 + lrow;
      int r = m0g + t * 64 + row; if (r > cnt - 1) r = cnt - 1;
      asrc[t][is] = hdn + (size_t)(eb + r) * DC + scol;
    }
#pragma unroll
  for (int is = 0; is < 4; ++is) {
    int row = (wid * 4 + is) * 8 + lrow;
    bsrc[is] = w2e + (size_t)(n0 + row) * DFF_ + scol;
  }

  f32x4 acc[2][2][4];
#pragma unroll
  for (int t = 0; t < 2; ++t)
#pragma unroll
    for (int i = 0; i < 2; ++i)
#pragma unroll
      for (int j = 0; j < 4; ++j) acc[t][i][j] = (f32x4){0.f, 0.f, 0.f, 0.f};

  for (int k0 = 0; k0 < DC; k0 += 64) {
    __syncthreads();
#pragma unroll
    for (int t = 0; t < 2; ++t)
#pragma unroll
      for (int is = 0; is < 2; ++is)
        gload16(asrc[t][is] + k0, &sA[t][(wid * 2 + is) * 512]);
#pragma unroll
    for (int is = 0; is < 4; ++is)
      gload16(bsrc[is] + k0, &sB[(wid * 4 + is) * 512]);
    __syncthreads();
#pragma unroll
    for (int s = 0; s < 2; ++s) {
      bf16x8 bfr[4];
#pragma unroll
      for (int j = 0; j < 4; ++j) {
        int row = wn * 64 + j * 16 + (lane & 15);
        bfr[j] = *(const bf16x8*)(&sB[row * 64 + (((s * 4 + (lane >> 4)) ^ (row & 7)) * 8)]);
      }
#pragma unroll
      for (int t = 0; t < 2; ++t) {
        bf16x8 af[2];
#pragma unroll
        for (int i = 0; i < 2; ++i) {
          int row = wm * 32 + i * 16 + (lane & 15);
          af[i] = *(const bf16x8*)(&sA[t][row * 64 + (((s * 4 + (lane >> 4)) ^ (row & 7)) * 8)]);
        }
#pragma unroll
        for (int i = 0; i < 2; ++i)
#pragma unroll
          for (int j = 0; j < 4; ++j)
            acc[t][i][j] = __builtin_amdgcn_mfma_f32_16x16x32_bf16(af[i], bfr[j], acc[t][i][j], 0, 0, 0);
      }
    }
  }

  int cl = lane & 15, rg = lane >> 4;
  float b2v[4];
#pragma unroll
  for (int j = 0; j < 4; ++j)
    b2v[j] = addb ? b2[e * H_ + n0 + wn * 64 + j * 16 + cl] : 0.0f;
#pragma unroll
  for (int t = 0; t < 2; ++t)
#pragma unroll
    for (int i = 0; i < 2; ++i) {
      int rbase = m0g + t * 64 + wm * 32 + i * 16 + rg * 4;
#pragma unroll
      for (int r = 0; r < 4; ++r) {
        int gr = rbase + r;
        if (gr < cnt) {
          int slot = lst[gr];
          float wgt = slotw[slot];
          float* orow = out + (size_t)(slot >> 1) * H_ + n0 + wn * 64 + cl;
#pragma unroll
          for (int j = 0; j < 4; ++j)
            atomicAdd(&orow[j * 16], wgt * (acc[t][i][j][r] + b2v[j]));
        }
      }
    }
}

extern "C" void kernel_launch(void* const* d_in, const int* in_sizes, int n_in,
                              void* d_out, int out_size, void* d_ws, size_t ws_size,
                              hipStream_t stream) {
  const float* x  = (const float*)d_in[0];
  const float* gw = (const float*)d_in[1];
  const float* w1 = (const float*)d_in[2];
  const float* b1 = (const float*)d_in[3];
  const float* w2 = (const float*)d_in[4];
  const float* b2 = (const float*)d_in[5];
  float* out = (float*)d_out;

  char* ws = (char*)d_ws;
  size_t off = 0;
  auto alloc = [&](size_t bytes) -> void* {
    void* p = ws + off; off += (bytes + 255) & ~(size_t)255; return p;
  };
  int*    counts = (int*)alloc(256);
  int*    ebase  = (int*)alloc(256);
  int*    lslot  = (int*)alloc((size_t)E_ * T_ * 4);
  float*  slotw  = (float*)alloc((size_t)NSLOT * 4);
  int*    slote  = (int*)alloc((size_t)NSLOT * 4);
  ushort* w1t    = (ushort*)alloc((size_t)E_ * DFF_ * H_ * 2);
  ushort* w2t    = (ushort*)alloc((size_t)E_ * H_ * DFF_ * 2);
  ushort* xb     = (ushort*)alloc((size_t)T_ * H_ * 2);

  int NC = 1;   // DFF chunking factor, only >1 if ws is tight
  while (NC < 16 && off + (size_t)NSLOT * (DFF_ / NC) * 2 > ws_size) NC *= 2;
  int DC = DFF_ / NC;
  ushort* hdn = (ushort*)alloc((size_t)NSLOT * DC * 2);

  prep_kernel<<<8192, 256, 0, stream>>>(x, gw, w1, w2, xb, slotw, slote, w1t, w2t, out);
  listbuild_kernel<<<1, 1024, 0, stream>>>(slote, counts, ebase, lslot);

  for (int c = 0; c < NC; ++c) {
    gemm1_kernel<<<E_ * (DC / 128) * (T_ / 64), 256, 0, stream>>>(
        xb, w1t, b1, counts, ebase, lslot, hdn, c * DC, DC);
    gemm2_kernel<<<E_ * (H_ / 128) * (T_ / 128), 256, 0, stream>>>(
        hdn, w2t, b2, slotw, counts, ebase, lslot, out, c * DC, DC, c == NC - 1);
  }
}